// Round 1
// baseline (181.914 us; speedup 1.0000x reference)
//
#include <hip/hip_runtime.h>

// Problem constants (from reference setup_inputs):
//   B=4, H=4, S=8, N=32768, W=32 -> P=W^3=32768, C=128, F=C/H=32
#define P_W3 32768
#define F_DIM 32
#define S_DIM 8
#define N_DIM 32768
#define BH_DIM 16   // B*H
#define NXCD 8      // MI355X XCD count

typedef _Float16 half8 __attribute__((ext_vector_type(8)));  // 16 B
typedef float    f32x4 __attribute__((ext_vector_type(4)));  // 16 B, clang-native

// ---------------------------------------------------------------------------
// XCD-pinned bh decomposition. Grid = 16 bh * 512 tiles = 8192 blocks.
// Default dispatch round-robins blockIdx across the 8 XCDs; we exploit that:
//   xcd  = blk & 7        -> which XCD this block lands on
//   slot = blk >> 3       -> 0..1023 sequence position within that XCD
//   bh   = 2*xcd + (slot >> 9)  -> each XCD owns exactly 2 bh, in sequence
// Per-XCD live T working set becomes one 2 MiB bh slice (fits 4 MiB L2),
// with no cross-XCD replication of slices. Bijective since 8192 % 8 == 0.
// ---------------------------------------------------------------------------
__device__ __forceinline__ void xcd_bh_tile(int blk, int& bh, int& tile) {
    const int xcd  = blk & (NXCD - 1);
    const int slot = blk >> 3;          // 0..1023
    bh   = 2 * xcd + (slot >> 9);       // 0..15
    tile = slot & 511;                  // 0..511
}

// ---------------------------------------------------------------------------
// Kernel 1: transpose + convert conv [bh, f, p] fp32 -> T [bh, p, f] fp16.
// One gather target becomes a contiguous 64 B chunk. conv loads nontemporal
// (streamed once) so they don't evict T from L2/L3. bh is pinned to the same
// XCD that will gather from it, so T lines stay dirty in that XCD's L2.
// ---------------------------------------------------------------------------
__global__ __launch_bounds__(256) void transpose_f16_kernel(
    const float* __restrict__ conv, _Float16* __restrict__ T) {
    int bh, pt;
    xcd_bh_tile(blockIdx.x, bh, pt);
    const int p0 = pt * 64;

    __shared__ float tile[F_DIM][65];         // stride 65: 2-way max on readout

    const float* src = conv + (size_t)bh * F_DIM * P_W3 + p0;
    {
        const int pp = (threadIdx.x & 15) * 4;
        const int f  = threadIdx.x >> 4;      // 0..15
#pragma unroll
        for (int k = 0; k < 2; ++k) {
            const f32x4 v = __builtin_nontemporal_load(
                (const f32x4*)(src + (size_t)(f + 16 * k) * P_W3 + pp));
            tile[f + 16 * k][pp + 0] = v.x;
            tile[f + 16 * k][pp + 1] = v.y;
            tile[f + 16 * k][pp + 2] = v.z;
            tile[f + 16 * k][pp + 3] = v.w;
        }
    }
    __syncthreads();

    _Float16* dst = T + ((size_t)bh * P_W3 + p0) * F_DIM;
    {
        const int f0 = (threadIdx.x & 3) * 8;
        const int p  = threadIdx.x >> 2;      // 0..63
        half8 hv;
#pragma unroll
        for (int j = 0; j < 8; ++j) hv[j] = (_Float16)tile[f0 + j][p];
        *(half8*)(dst + (size_t)p * F_DIM + f0) = hv;   // 64B/4 lanes contiguous
    }
}

// ---------------------------------------------------------------------------
// Kernel 2: wave-cooperative fp16 gather. 4 lanes per (s,n); lane q loads the
// 16 B sub-chunk of the 64 B feature row T[id*32 + q*8 .. +7]. A wave covers
// 16 gathers per instruction, fully coalesced per gather. fp32 accumulate.
// idx/lc loads and out stores are nontemporal to keep T resident in L2/L3.
// bh pinned per-XCD (matching kernel 1) so T gathers hit the local L2.
// ---------------------------------------------------------------------------
__global__ __launch_bounds__(256) void gather_f16_kernel(
    const float* __restrict__ lc, const int* __restrict__ idx,
    const _Float16* __restrict__ T, float* __restrict__ out) {
    int bh, nt;
    xcd_bh_tile(blockIdx.x, bh, nt);
    const int nb = nt * 64;
    const int t  = threadIdx.x;
    const int q  = t & 3;                     // 16B sub-chunk 0..3
    const int nl = t >> 2;                    // local n 0..63
    const int n  = nb + nl;

    const _Float16* Tb = T + (size_t)bh * P_W3 * F_DIM + q * 8;
    const int*   ip = idx + (size_t)bh * S_DIM * N_DIM + n;
    const float* wp = lc  + (size_t)bh * S_DIM * N_DIM + n;

    float acc[8];
#pragma unroll
    for (int j = 0; j < 8; ++j) acc[j] = 0.f;

#pragma unroll
    for (int s = 0; s < S_DIM; ++s) {
        const int   id = __builtin_nontemporal_load(ip + (size_t)s * N_DIM);
        const float w  = __builtin_nontemporal_load(wp + (size_t)s * N_DIM);
        const half8 v  = *(const half8*)(Tb + (size_t)id * F_DIM);
#pragma unroll
        for (int j = 0; j < 8; ++j) acc[j] += w * (float)v[j];
    }

    // LDS transpose so out stores are coalesced 128B segments over n.
    __shared__ float smem[64][33];
#pragma unroll
    for (int j = 0; j < 8; ++j) smem[nl][q * 8 + j] = acc[j];
    __syncthreads();

    const int f  = t >> 3;                    // 0..31
    const int c0 = t & 7;
#pragma unroll
    for (int k = 0; k < 2; ++k) {
        const int c = c0 + 8 * k;             // n quad 0..15
        f32x4 o;
        o.x = smem[c * 4 + 0][f];
        o.y = smem[c * 4 + 1][f];
        o.z = smem[c * 4 + 2][f];
        o.w = smem[c * 4 + 3][f];
        __builtin_nontemporal_store(
            o, (f32x4*)(out + ((size_t)bh * F_DIM + f) * N_DIM + nb + c * 4));
    }
}

// ---------------------------------------------------------------------------
// Fallback (only if ws too small): gather directly from [B,C,P] layout.
// ---------------------------------------------------------------------------
__global__ __launch_bounds__(256) void gather_direct_kernel(
    const float* __restrict__ lc, const int* __restrict__ idx,
    const float* __restrict__ conv, float* __restrict__ out) {
    const int t  = blockIdx.x * 256 + threadIdx.x;
    const int n  = t & (N_DIM - 1);
    const int bh = t >> 15;

    const float* Cb = conv + (size_t)bh * F_DIM * P_W3;
    const int*   ip = idx + (size_t)bh * S_DIM * N_DIM + n;
    const float* wp = lc  + (size_t)bh * S_DIM * N_DIM + n;

    float acc[F_DIM];
#pragma unroll
    for (int f = 0; f < F_DIM; ++f) acc[f] = 0.f;

#pragma unroll
    for (int s = 0; s < S_DIM; ++s) {
        const int   id = ip[(size_t)s * N_DIM];
        const float w  = wp[(size_t)s * N_DIM];
#pragma unroll
        for (int f = 0; f < F_DIM; ++f)
            acc[f] += w * Cb[(size_t)f * P_W3 + id];
    }

    float* op = out + (size_t)bh * F_DIM * N_DIM + n;
#pragma unroll
    for (int f = 0; f < F_DIM; ++f)
        op[(size_t)f * N_DIM] = acc[f];
}

extern "C" void kernel_launch(void* const* d_in, const int* in_sizes, int n_in,
                              void* d_out, int out_size, void* d_ws, size_t ws_size,
                              hipStream_t stream) {
    const float* lc   = (const float*)d_in[0];   // [B,H,S,N] fp32
    const int*   idx  = (const int*)d_in[1];     // [B,H,S,N] int32
    const float* conv = (const float*)d_in[2];   // [B,C,W,W,W] fp32
    float*       out  = (float*)d_out;           // [B,C,N] fp32

    const size_t need = (size_t)BH_DIM * P_W3 * F_DIM * sizeof(_Float16);  // 32 MiB
    if (ws_size >= need) {
        _Float16* T = (_Float16*)d_ws;
        transpose_f16_kernel<<<BH_DIM * (P_W3 / 64), 256, 0, stream>>>(conv, T);
        gather_f16_kernel<<<BH_DIM * (N_DIM / 64), 256, 0, stream>>>(lc, idx, T, out);
    } else {
        gather_direct_kernel<<<(BH_DIM * N_DIM) / 256, 256, 0, stream>>>(lc, idx, conv, out);
    }
}

// Round 2
// 180.851 us; speedup vs baseline: 1.0059x; 1.0059x over previous
//
#include <hip/hip_runtime.h>

// Problem constants (from reference setup_inputs):
//   B=4, H=4, S=8, N=32768, W=32 -> P=W^3=32768, C=128, F=C/H=32
#define P_W3 32768
#define F_DIM 32
#define S_DIM 8
#define N_DIM 32768
#define BH_DIM 16   // B*H
#define NXCD 8      // MI355X XCD count

typedef _Float16 half8 __attribute__((ext_vector_type(8)));  // 16 B
typedef float    f32x4 __attribute__((ext_vector_type(4)));  // 16 B, clang-native

// ---------------------------------------------------------------------------
// XCD-pinned bh decomposition. Grid = 16 bh * 512 tiles = 8192 blocks.
// Default dispatch round-robins blockIdx across the 8 XCDs; we exploit that:
//   xcd  = blk & 7        -> which XCD this block lands on
//   slot = blk >> 3       -> 0..1023 sequence position within that XCD
//   bh   = 2*xcd + (slot >> 9)  -> each XCD owns exactly 2 bh, in sequence
// Per-XCD live T working set becomes one 2 MiB bh slice (fits 4 MiB L2),
// with no cross-XCD replication. Verified round 1: FETCH 133->34 MB.
// ---------------------------------------------------------------------------
__device__ __forceinline__ void xcd_bh_tile(int blk, int& bh, int& tile) {
    const int xcd  = blk & (NXCD - 1);
    const int slot = blk >> 3;          // 0..1023
    bh   = 2 * xcd + (slot >> 9);       // 0..15
    tile = slot & 511;                  // 0..511
}

// ---------------------------------------------------------------------------
// Kernel 1: transpose + convert conv [bh, f, p] fp32 -> T [bh, p, f] fp16.
// One gather target becomes a contiguous 64 B chunk. conv loads nontemporal
// (streamed once) so they don't evict T from L2/L3. bh is pinned to the same
// XCD that will gather from it, so T lines stay dirty in that XCD's L2.
// ---------------------------------------------------------------------------
__global__ __launch_bounds__(256) void transpose_f16_kernel(
    const float* __restrict__ conv, _Float16* __restrict__ T) {
    int bh, pt;
    xcd_bh_tile(blockIdx.x, bh, pt);
    const int p0 = pt * 64;

    __shared__ float tile[F_DIM][65];         // stride 65: 2-way max on readout

    const float* src = conv + (size_t)bh * F_DIM * P_W3 + p0;
    {
        const int pp = (threadIdx.x & 15) * 4;
        const int f  = threadIdx.x >> 4;      // 0..15
#pragma unroll
        for (int k = 0; k < 2; ++k) {
            const f32x4 v = __builtin_nontemporal_load(
                (const f32x4*)(src + (size_t)(f + 16 * k) * P_W3 + pp));
            tile[f + 16 * k][pp + 0] = v.x;
            tile[f + 16 * k][pp + 1] = v.y;
            tile[f + 16 * k][pp + 2] = v.z;
            tile[f + 16 * k][pp + 3] = v.w;
        }
    }
    __syncthreads();

    _Float16* dst = T + ((size_t)bh * P_W3 + p0) * F_DIM;
    {
        const int f0 = (threadIdx.x & 3) * 8;
        const int p  = threadIdx.x >> 2;      // 0..63
        half8 hv;
#pragma unroll
        for (int j = 0; j < 8; ++j) hv[j] = (_Float16)tile[f0 + j][p];
        *(half8*)(dst + (size_t)p * F_DIM + f0) = hv;   // 64B/4 lanes contiguous
    }
}

// ---------------------------------------------------------------------------
// Kernel 2: wave-cooperative fp16 gather, MLP-maximized. 4 lanes per (s,n);
// lane q loads the 16 B sub-chunk of the 64 B feature row T[id*32 + q*8..+7].
// Three unrolled phases so ALL independent loads are in flight at once:
//   phase 1: issue 8 idx + 8 w stream loads (independent, affine addresses)
//   phase 2: issue 8 T-gathers into a register array (each waits only for
//            its own idx via in-order vmcnt)
//   phase 3: accumulate (waits for gathers, all already in flight)
// This replaces the round-1 serial chain (load idx -> wait -> gather -> wait
// -> fma, ~8 full latencies per wave, VGPR_Count=28) with ~1 latency per
// wave at ~64 VGPRs. All array indices are compile-time (no scratch).
// ---------------------------------------------------------------------------
__global__ __launch_bounds__(256) void gather_f16_kernel(
    const float* __restrict__ lc, const int* __restrict__ idx,
    const _Float16* __restrict__ T, float* __restrict__ out) {
    int bh, nt;
    xcd_bh_tile(blockIdx.x, bh, nt);
    const int nb = nt * 64;
    const int t  = threadIdx.x;
    const int q  = t & 3;                     // 16B sub-chunk 0..3
    const int nl = t >> 2;                    // local n 0..63
    const int n  = nb + nl;

    const _Float16* Tb = T + (size_t)bh * P_W3 * F_DIM + q * 8;
    const int*   ip = idx + (size_t)bh * S_DIM * N_DIM + n;
    const float* wp = lc  + (size_t)bh * S_DIM * N_DIM + n;

    // Phase 1: all stream loads in flight.
    int   ids[S_DIM];
    float wts[S_DIM];
#pragma unroll
    for (int s = 0; s < S_DIM; ++s) {
        ids[s] = __builtin_nontemporal_load(ip + (size_t)s * N_DIM);
        wts[s] = __builtin_nontemporal_load(wp + (size_t)s * N_DIM);
    }

    // Phase 2: all gathers in flight (16 B per lane, 4 lanes per 64 B row).
    half8 v[S_DIM];
#pragma unroll
    for (int s = 0; s < S_DIM; ++s)
        v[s] = *(const half8*)(Tb + (size_t)ids[s] * F_DIM);

    // Phase 3: accumulate in fp32.
    float acc[8];
#pragma unroll
    for (int j = 0; j < 8; ++j) acc[j] = 0.f;
#pragma unroll
    for (int s = 0; s < S_DIM; ++s) {
        const float w = wts[s];
#pragma unroll
        for (int j = 0; j < 8; ++j) acc[j] += w * (float)v[s][j];
    }

    // LDS transpose so out stores are coalesced 128B segments over n.
    __shared__ float smem[64][33];
#pragma unroll
    for (int j = 0; j < 8; ++j) smem[nl][q * 8 + j] = acc[j];
    __syncthreads();

    const int f  = t >> 3;                    // 0..31
    const int c0 = t & 7;
#pragma unroll
    for (int k = 0; k < 2; ++k) {
        const int c = c0 + 8 * k;             // n quad 0..15
        f32x4 o;
        o.x = smem[c * 4 + 0][f];
        o.y = smem[c * 4 + 1][f];
        o.z = smem[c * 4 + 2][f];
        o.w = smem[c * 4 + 3][f];
        __builtin_nontemporal_store(
            o, (f32x4*)(out + ((size_t)bh * F_DIM + f) * N_DIM + nb + c * 4));
    }
}

// ---------------------------------------------------------------------------
// Fallback (only if ws too small): gather directly from [B,C,P] layout.
// ---------------------------------------------------------------------------
__global__ __launch_bounds__(256) void gather_direct_kernel(
    const float* __restrict__ lc, const int* __restrict__ idx,
    const float* __restrict__ conv, float* __restrict__ out) {
    const int t  = blockIdx.x * 256 + threadIdx.x;
    const int n  = t & (N_DIM - 1);
    const int bh = t >> 15;

    const float* Cb = conv + (size_t)bh * F_DIM * P_W3;
    const int*   ip = idx + (size_t)bh * S_DIM * N_DIM + n;
    const float* wp = lc  + (size_t)bh * S_DIM * N_DIM + n;

    float acc[F_DIM];
#pragma unroll
    for (int f = 0; f < F_DIM; ++f) acc[f] = 0.f;

#pragma unroll
    for (int s = 0; s < S_DIM; ++s) {
        const int   id = ip[(size_t)s * N_DIM];
        const float w  = wp[(size_t)s * N_DIM];
#pragma unroll
        for (int f = 0; f < F_DIM; ++f)
            acc[f] += w * Cb[(size_t)f * P_W3 + id];
    }

    float* op = out + (size_t)bh * F_DIM * N_DIM + n;
#pragma unroll
    for (int f = 0; f < F_DIM; ++f)
        op[(size_t)f * N_DIM] = acc[f];
}

extern "C" void kernel_launch(void* const* d_in, const int* in_sizes, int n_in,
                              void* d_out, int out_size, void* d_ws, size_t ws_size,
                              hipStream_t stream) {
    const float* lc   = (const float*)d_in[0];   // [B,H,S,N] fp32
    const int*   idx  = (const int*)d_in[1];     // [B,H,S,N] int32
    const float* conv = (const float*)d_in[2];   // [B,C,W,W,W] fp32
    float*       out  = (float*)d_out;           // [B,C,N] fp32

    const size_t need = (size_t)BH_DIM * P_W3 * F_DIM * sizeof(_Float16);  // 32 MiB
    if (ws_size >= need) {
        _Float16* T = (_Float16*)d_ws;
        transpose_f16_kernel<<<BH_DIM * (P_W3 / 64), 256, 0, stream>>>(conv, T);
        gather_f16_kernel<<<BH_DIM * (N_DIM / 64), 256, 0, stream>>>(lc, idx, T, out);
    } else {
        gather_direct_kernel<<<(BH_DIM * N_DIM) / 256, 256, 0, stream>>>(lc, idx, conv, out);
    }
}

// Round 3
// 172.743 us; speedup vs baseline: 1.0531x; 1.0469x over previous
//
#include <hip/hip_runtime.h>

// Problem constants (from reference setup_inputs):
//   B=4, H=4, S=8, N=32768, W=32 -> P=W^3=32768, C=128, F=C/H=32
#define P_W3 32768
#define F_DIM 32
#define S_DIM 8
#define N_DIM 32768
#define BH_DIM 16   // B*H
#define NXCD 8      // MI355X XCD count

typedef _Float16 half8 __attribute__((ext_vector_type(8)));  // 16 B
typedef float    f32x4 __attribute__((ext_vector_type(4)));  // 16 B, clang-native

// ---------------------------------------------------------------------------
// XCD-pinned bh decomposition. Grid = 16 bh * 512 tiles = 8192 blocks.
// Default dispatch round-robins blockIdx across the 8 XCDs; we exploit that:
//   xcd  = blk & 7        -> which XCD this block lands on
//   slot = blk >> 3       -> 0..1023 sequence position within that XCD
//   bh   = 2*xcd + (slot >> 9)  -> each XCD owns exactly 2 bh, in sequence
// Per-XCD live T working set becomes one 2 MiB bh slice (fits 4 MiB L2),
// with no cross-XCD replication. Verified round 1: FETCH 133->34 MB.
// ---------------------------------------------------------------------------
__device__ __forceinline__ void xcd_bh_tile(int blk, int& bh, int& tile) {
    const int xcd  = blk & (NXCD - 1);
    const int slot = blk >> 3;          // 0..1023
    bh   = 2 * xcd + (slot >> 9);       // 0..15
    tile = slot & 511;                  // 0..511
}

// ---------------------------------------------------------------------------
// Kernel 1: transpose + convert conv [bh, f, p] fp32 -> T [bh, p, f] fp16.
// One gather target becomes a contiguous 64 B chunk. conv loads nontemporal
// (streamed once) so they don't evict T from L2/L3. bh is pinned to the same
// XCD that will gather from it, so T lines stay dirty in that XCD's L2.
// ---------------------------------------------------------------------------
__global__ __launch_bounds__(256) void transpose_f16_kernel(
    const float* __restrict__ conv, _Float16* __restrict__ T) {
    int bh, pt;
    xcd_bh_tile(blockIdx.x, bh, pt);
    const int p0 = pt * 64;

    __shared__ float tile[F_DIM][65];         // stride 65: 2-way max on readout

    const float* src = conv + (size_t)bh * F_DIM * P_W3 + p0;
    {
        const int pp = (threadIdx.x & 15) * 4;
        const int f  = threadIdx.x >> 4;      // 0..15
#pragma unroll
        for (int k = 0; k < 2; ++k) {
            const f32x4 v = __builtin_nontemporal_load(
                (const f32x4*)(src + (size_t)(f + 16 * k) * P_W3 + pp));
            tile[f + 16 * k][pp + 0] = v.x;
            tile[f + 16 * k][pp + 1] = v.y;
            tile[f + 16 * k][pp + 2] = v.z;
            tile[f + 16 * k][pp + 3] = v.w;
        }
    }
    __syncthreads();

    _Float16* dst = T + ((size_t)bh * P_W3 + p0) * F_DIM;
    {
        const int f0 = (threadIdx.x & 3) * 8;
        const int p  = threadIdx.x >> 2;      // 0..63
        half8 hv;
#pragma unroll
        for (int j = 0; j < 8; ++j) hv[j] = (_Float16)tile[f0 + j][p];
        *(half8*)(dst + (size_t)p * F_DIM + f0) = hv;   // 64B/4 lanes contiguous
    }
}

// ---------------------------------------------------------------------------
// Kernel 2: wave-cooperative fp16 gather, MLP-maximized. 4 lanes per (s,n);
// lane q loads the 16 B sub-chunk of the 64 B feature row T[id*32 + q*8..+7].
// Three phases pinned with sched_barrier(0) so the compiler CANNOT re-fuse
// them into a serial load->wait->gather->wait chain (round 2 failure mode:
// VGPR_Count stayed 28, code unchanged). With order pinned, waitcnt insertion
// produces counted waits: all 16 stream loads in flight, then all 8 gathers
// in flight -> ~2 memory latencies per wave instead of ~8-16.
// ---------------------------------------------------------------------------
__global__ __launch_bounds__(256) void gather_f16_kernel(
    const float* __restrict__ lc, const int* __restrict__ idx,
    const _Float16* __restrict__ T, float* __restrict__ out) {
    int bh, nt;
    xcd_bh_tile(blockIdx.x, bh, nt);
    const int nb = nt * 64;
    const int t  = threadIdx.x;
    const int q  = t & 3;                     // 16B sub-chunk 0..3
    const int nl = t >> 2;                    // local n 0..63
    const int n  = nb + nl;

    const _Float16* Tb = T + (size_t)bh * P_W3 * F_DIM + q * 8;
    const int*   ip = idx + (size_t)bh * S_DIM * N_DIM + n;
    const float* wp = lc  + (size_t)bh * S_DIM * N_DIM + n;

    // Phase 1: all 16 stream loads issued (independent affine addresses).
    int   ids[S_DIM];
    float wts[S_DIM];
#pragma unroll
    for (int s = 0; s < S_DIM; ++s) {
        ids[s] = __builtin_nontemporal_load(ip + (size_t)s * N_DIM);
        wts[s] = __builtin_nontemporal_load(wp + (size_t)s * N_DIM);
    }
    __builtin_amdgcn_sched_barrier(0);   // nothing crosses: loads stay batched

    // Phase 2: all 8 gathers issued (16 B per lane, 4 lanes per 64 B row).
    half8 v[S_DIM];
#pragma unroll
    for (int s = 0; s < S_DIM; ++s)
        v[s] = *(const half8*)(Tb + (size_t)ids[s] * F_DIM);
    __builtin_amdgcn_sched_barrier(0);   // gathers stay batched ahead of use

    // Phase 3: accumulate in fp32.
    float acc[8];
#pragma unroll
    for (int j = 0; j < 8; ++j) acc[j] = 0.f;
#pragma unroll
    for (int s = 0; s < S_DIM; ++s) {
        const float w = wts[s];
#pragma unroll
        for (int j = 0; j < 8; ++j) acc[j] += w * (float)v[s][j];
    }

    // LDS transpose so out stores are coalesced 128B segments over n.
    __shared__ float smem[64][33];
#pragma unroll
    for (int j = 0; j < 8; ++j) smem[nl][q * 8 + j] = acc[j];
    __syncthreads();

    const int f  = t >> 3;                    // 0..31
    const int c0 = t & 7;
#pragma unroll
    for (int k = 0; k < 2; ++k) {
        const int c = c0 + 8 * k;             // n quad 0..15
        f32x4 o;
        o.x = smem[c * 4 + 0][f];
        o.y = smem[c * 4 + 1][f];
        o.z = smem[c * 4 + 2][f];
        o.w = smem[c * 4 + 3][f];
        __builtin_nontemporal_store(
            o, (f32x4*)(out + ((size_t)bh * F_DIM + f) * N_DIM + nb + c * 4));
    }
}

// ---------------------------------------------------------------------------
// Fallback (only if ws too small): gather directly from [B,C,P] layout.
// ---------------------------------------------------------------------------
__global__ __launch_bounds__(256) void gather_direct_kernel(
    const float* __restrict__ lc, const int* __restrict__ idx,
    const float* __restrict__ conv, float* __restrict__ out) {
    const int t  = blockIdx.x * 256 + threadIdx.x;
    const int n  = t & (N_DIM - 1);
    const int bh = t >> 15;

    const float* Cb = conv + (size_t)bh * F_DIM * P_W3;
    const int*   ip = idx + (size_t)bh * S_DIM * N_DIM + n;
    const float* wp = lc  + (size_t)bh * S_DIM * N_DIM + n;

    float acc[F_DIM];
#pragma unroll
    for (int f = 0; f < F_DIM; ++f) acc[f] = 0.f;

#pragma unroll
    for (int s = 0; s < S_DIM; ++s) {
        const int   id = ip[(size_t)s * N_DIM];
        const float w  = wp[(size_t)s * N_DIM];
#pragma unroll
        for (int f = 0; f < F_DIM; ++f)
            acc[f] += w * Cb[(size_t)f * P_W3 + id];
    }

    float* op = out + (size_t)bh * F_DIM * N_DIM + n;
#pragma unroll
    for (int f = 0; f < F_DIM; ++f)
        op[(size_t)f * N_DIM] = acc[f];
}

extern "C" void kernel_launch(void* const* d_in, const int* in_sizes, int n_in,
                              void* d_out, int out_size, void* d_ws, size_t ws_size,
                              hipStream_t stream) {
    const float* lc   = (const float*)d_in[0];   // [B,H,S,N] fp32
    const int*   idx  = (const int*)d_in[1];     // [B,H,S,N] int32
    const float* conv = (const float*)d_in[2];   // [B,C,W,W,W] fp32
    float*       out  = (float*)d_out;           // [B,C,N] fp32

    const size_t need = (size_t)BH_DIM * P_W3 * F_DIM * sizeof(_Float16);  // 32 MiB
    if (ws_size >= need) {
        _Float16* T = (_Float16*)d_ws;
        transpose_f16_kernel<<<BH_DIM * (P_W3 / 64), 256, 0, stream>>>(conv, T);
        gather_f16_kernel<<<BH_DIM * (N_DIM / 64), 256, 0, stream>>>(lc, idx, T, out);
    } else {
        gather_direct_kernel<<<(BH_DIM * N_DIM) / 256, 256, 0, stream>>>(lc, idx, conv, out);
    }
}

// Round 4
// 161.001 us; speedup vs baseline: 1.1299x; 1.0729x over previous
//
#include <hip/hip_runtime.h>

// Problem constants (from reference setup_inputs):
//   B=4, H=4, S=8, N=32768, W=32 -> P=W^3=32768, C=128, F=C/H=32
#define P_W3 32768
#define F_DIM 32
#define S_DIM 8
#define N_DIM 32768
#define BH_DIM 16   // B*H
#define NXCD 8      // MI355X XCD count

typedef _Float16 half8 __attribute__((ext_vector_type(8)));  // 16 B
typedef float    f32x4 __attribute__((ext_vector_type(4)));  // 16 B, clang-native

// ---------------------------------------------------------------------------
// XCD-pinned bh decomposition. Grid = 16 bh * 512 tiles = 8192 blocks.
//   xcd  = blk & 7; slot = blk >> 3; bh = 2*xcd + (slot >> 9)
// Per-XCD live T working set = one 2 MiB bh slice (fits 4 MiB L2), no
// cross-XCD replication. Verified round 1: FETCH 133 -> 34 MB.
// ---------------------------------------------------------------------------
__device__ __forceinline__ void xcd_bh_tile(int blk, int& bh, int& tile) {
    const int xcd  = blk & (NXCD - 1);
    const int slot = blk >> 3;          // 0..1023
    bh   = 2 * xcd + (slot >> 9);       // 0..15
    tile = slot & 511;                  // 0..511
}

// ---------------------------------------------------------------------------
// Kernel 1: transpose + convert conv [bh, f, p] fp32 -> T [bh, p, f] fp16.
// ---------------------------------------------------------------------------
__global__ __launch_bounds__(256) void transpose_f16_kernel(
    const float* __restrict__ conv, _Float16* __restrict__ T) {
    int bh, pt;
    xcd_bh_tile(blockIdx.x, bh, pt);
    const int p0 = pt * 64;

    __shared__ float tile[F_DIM][65];         // stride 65: 2-way max on readout

    const float* src = conv + (size_t)bh * F_DIM * P_W3 + p0;
    {
        const int pp = (threadIdx.x & 15) * 4;
        const int f  = threadIdx.x >> 4;      // 0..15
#pragma unroll
        for (int k = 0; k < 2; ++k) {
            const f32x4 v = __builtin_nontemporal_load(
                (const f32x4*)(src + (size_t)(f + 16 * k) * P_W3 + pp));
            tile[f + 16 * k][pp + 0] = v.x;
            tile[f + 16 * k][pp + 1] = v.y;
            tile[f + 16 * k][pp + 2] = v.z;
            tile[f + 16 * k][pp + 3] = v.w;
        }
    }
    __syncthreads();

    _Float16* dst = T + ((size_t)bh * P_W3 + p0) * F_DIM;
    {
        const int f0 = (threadIdx.x & 3) * 8;
        const int p  = threadIdx.x >> 2;      // 0..63
        half8 hv;
#pragma unroll
        for (int j = 0; j < 8; ++j) hv[j] = (_Float16)tile[f0 + j][p];
        *(half8*)(dst + (size_t)p * F_DIM + f0) = hv;   // 64B/4 lanes contiguous
    }
}

// ---------------------------------------------------------------------------
// Kernel 2: gather with FORCED memory-level parallelism.
// Round-3 post-mortem: compiler register-minimized (VGPR=32) and serialized
// the loads into a ~16-deep latency chain despite sched_barrier. Fixes:
//   (a) idx/w staged cooperatively into LDS: block loads each element ONCE
//       (was 4x redundant per q-split), via 4 independent coalesced loads
//       per thread -> one batched HBM round trip per block.
//   (b) the 8 T-gathers are issued as volatile inline-asm
//       global_load_dwordx4 with distinct forced-live destinations and a
//       single explicit s_waitcnt vmcnt(0) + sched_barrier(0) (rule #18).
//       Hardware keeps 8 loads in flight; allocator cannot serialize.
// Compiler's own vmcnt scoreboard is drained at __syncthreads before the
// asm block, so its later counted waits stay consistent.
// ---------------------------------------------------------------------------
__global__ __launch_bounds__(256) void gather_f16_kernel(
    const float* __restrict__ lc, const int* __restrict__ idx,
    const _Float16* __restrict__ T, float* __restrict__ out) {
    int bh, nt;
    xcd_bh_tile(blockIdx.x, bh, nt);
    const int nb = nt * 64;
    const int t  = threadIdx.x;
    const int q  = t & 3;                     // 16B sub-chunk 0..3
    const int nl = t >> 2;                    // local n 0..63

    __shared__ int   s_id[S_DIM][64];
    __shared__ float s_w [S_DIM][64];

    // Stage idx/w for this (bh, n-block) once per block. 512+512 elements,
    // 256 threads -> 2 idx + 2 w independent coalesced loads per thread.
    {
        const int*   ip0 = idx + (size_t)bh * S_DIM * N_DIM + nb;
        const float* wp0 = lc  + (size_t)bh * S_DIM * N_DIM + nb;
#pragma unroll
        for (int r = 0; r < 2; ++r) {
            const int e  = t + 256 * r;       // 0..511
            const int s  = e >> 6;            // 0..7
            const int nn = e & 63;
            s_id[s][nn] = __builtin_nontemporal_load(ip0 + (size_t)s * N_DIM + nn);
            s_w [s][nn] = __builtin_nontemporal_load(wp0 + (size_t)s * N_DIM + nn);
        }
    }
    __syncthreads();

    // Read this thread's 8 (id, w) pairs from LDS (4-lane broadcast reads).
    int   ids[S_DIM];
    float wts[S_DIM];
#pragma unroll
    for (int s = 0; s < S_DIM; ++s) {
        ids[s] = s_id[s][nl];
        wts[s] = s_w [s][nl];
    }

    // Issue all 8 gathers; each dest is a distinct forced-live 4-VGPR tuple.
    // Uniform SGPR-pair base (per-bh T slice), 32-bit voffset per lane.
    const _Float16* Tbase = T + (size_t)bh * P_W3 * F_DIM;
    f32x4 g[S_DIM];
#pragma unroll
    for (int s = 0; s < S_DIM; ++s) {
        const int voff = (ids[s] << 6) + (q << 4);   // id*64B + q*16B
        asm volatile("global_load_dwordx4 %0, %1, %2"
                     : "=v"(g[s])
                     : "v"(voff), "s"(Tbase)
                     : "memory");
    }
    asm volatile("s_waitcnt vmcnt(0)" ::: "memory");
    __builtin_amdgcn_sched_barrier(0);

    // Accumulate in fp32.
    float acc[8];
#pragma unroll
    for (int j = 0; j < 8; ++j) acc[j] = 0.f;
#pragma unroll
    for (int s = 0; s < S_DIM; ++s) {
        const half8 hv = __builtin_bit_cast(half8, g[s]);
        const float w  = wts[s];
#pragma unroll
        for (int j = 0; j < 8; ++j) acc[j] += w * (float)hv[j];
    }

    // LDS transpose so out stores are coalesced 128B segments over n.
    __shared__ float smem[64][33];
#pragma unroll
    for (int j = 0; j < 8; ++j) smem[nl][q * 8 + j] = acc[j];
    __syncthreads();

    const int f  = t >> 3;                    // 0..31
    const int c0 = t & 7;
#pragma unroll
    for (int k = 0; k < 2; ++k) {
        const int c = c0 + 8 * k;             // n quad 0..15
        f32x4 o;
        o.x = smem[c * 4 + 0][f];
        o.y = smem[c * 4 + 1][f];
        o.z = smem[c * 4 + 2][f];
        o.w = smem[c * 4 + 3][f];
        __builtin_nontemporal_store(
            o, (f32x4*)(out + ((size_t)bh * F_DIM + f) * N_DIM + nb + c * 4));
    }
}

// ---------------------------------------------------------------------------
// Fallback (only if ws too small): gather directly from [B,C,P] layout.
// ---------------------------------------------------------------------------
__global__ __launch_bounds__(256) void gather_direct_kernel(
    const float* __restrict__ lc, const int* __restrict__ idx,
    const float* __restrict__ conv, float* __restrict__ out) {
    const int t  = blockIdx.x * 256 + threadIdx.x;
    const int n  = t & (N_DIM - 1);
    const int bh = t >> 15;

    const float* Cb = conv + (size_t)bh * F_DIM * P_W3;
    const int*   ip = idx + (size_t)bh * S_DIM * N_DIM + n;
    const float* wp = lc  + (size_t)bh * S_DIM * N_DIM + n;

    float acc[F_DIM];
#pragma unroll
    for (int f = 0; f < F_DIM; ++f) acc[f] = 0.f;

#pragma unroll
    for (int s = 0; s < S_DIM; ++s) {
        const int   id = ip[(size_t)s * N_DIM];
        const float w  = wp[(size_t)s * N_DIM];
#pragma unroll
        for (int f = 0; f < F_DIM; ++f)
            acc[f] += w * Cb[(size_t)f * P_W3 + id];
    }

    float* op = out + (size_t)bh * F_DIM * N_DIM + n;
#pragma unroll
    for (int f = 0; f < F_DIM; ++f)
        op[(size_t)f * N_DIM] = acc[f];
}

extern "C" void kernel_launch(void* const* d_in, const int* in_sizes, int n_in,
                              void* d_out, int out_size, void* d_ws, size_t ws_size,
                              hipStream_t stream) {
    const float* lc   = (const float*)d_in[0];   // [B,H,S,N] fp32
    const int*   idx  = (const int*)d_in[1];     // [B,H,S,N] int32
    const float* conv = (const float*)d_in[2];   // [B,C,W,W,W] fp32
    float*       out  = (float*)d_out;           // [B,C,N] fp32

    const size_t need = (size_t)BH_DIM * P_W3 * F_DIM * sizeof(_Float16);  // 32 MiB
    if (ws_size >= need) {
        _Float16* T = (_Float16*)d_ws;
        transpose_f16_kernel<<<BH_DIM * (P_W3 / 64), 256, 0, stream>>>(conv, T);
        gather_f16_kernel<<<BH_DIM * (N_DIM / 64), 256, 0, stream>>>(lc, idx, T, out);
    } else {
        gather_direct_kernel<<<(BH_DIM * N_DIM) / 256, 256, 0, stream>>>(lc, idx, conv, out);
    }
}